// Round 8
// baseline (171.943 us; speedup 1.0000x reference)
//
#include <hip/hip_runtime.h>
#include <hip/hip_fp16.h>

#define B_ 16
#define N_ 512
#define D_ 64
#define K_ 8

// ---------------- ws layout ----------------
// wsu : [B][N][N] uint {kin*128 | (kout*128)<<16}   16,777,216 B
// Tin : [B][N][9][64] f16                            9,437,184 B
// Tout: [B][N][9][64] f16   (MUST follow Tin)        9,437,184 B
#define WSU_BYTES ((size_t)B_ * N_ * N_ * 4)
#define T_BYTES   ((size_t)B_ * N_ * (K_ + 1) * D_ * 2)
#define TROWB 1152        // (K+1)*D*2 bytes per j row
#define TOUT_OFF (T_BYTES / 2)   // Tout offset in ushorts

typedef __attribute__((ext_vector_type(8))) short bf8_t;   // 8 bf16
typedef __attribute__((ext_vector_type(4))) float f4_t;    // 4 f32 acc

__device__ __forceinline__ unsigned short f2bf(float x) {  // RNE f32->bf16
  union { float f; unsigned u; } c; c.f = x;
  unsigned r = c.u + 0x7FFFu + ((c.u >> 16) & 1u);
  return (unsigned short)(r >> 16);
}

__device__ __forceinline__ bf8_t pack_bf8(const float* p) {  // 8 f32 -> 8 bf16
  const float4 a = *(const float4*)p;
  const float4 b = *(const float4*)(p + 4);
  union { unsigned u[4]; bf8_t v; } r;
  r.u[0] = (unsigned)f2bf(a.x) | ((unsigned)f2bf(a.y) << 16);
  r.u[1] = (unsigned)f2bf(a.z) | ((unsigned)f2bf(a.w) << 16);
  r.u[2] = (unsigned)f2bf(b.x) | ((unsigned)f2bf(b.y) << 16);
  r.u[3] = (unsigned)f2bf(b.z) | ((unsigned)f2bf(b.w) << 16);
  return r.v;
}

// ---------- kernel A: transpose + pack PRE-SHIFTED edge byte-offsets ----------
__global__ __launch_bounds__(256) void prep_adj(const int* __restrict__ adj,
                                                unsigned* __restrict__ wsu) {
  __shared__ int ta[64][65];
  __shared__ int tb[64][65];
  const int blk = blockIdx.x;          // 1024
  const int xcd = blk & 7, rest = blk >> 3;
  const int b = xcd + 8 * (rest & 1);  // batch b -> XCD b%8
  const int tile = rest >> 1;          // 0..63
  const int i0 = (tile >> 3) * 64, j0 = (tile & 7) * 64;
  const int lane = threadIdx.x & 63, w = threadIdx.x >> 6;
  const int* ab = adj + (size_t)b * N_ * N_;
#pragma unroll
  for (int r = w; r < 64; r += 4) {
    ta[r][lane] = ab[(size_t)(i0 + r) * N_ + j0 + lane];
    tb[r][lane] = ab[(size_t)(j0 + r) * N_ + i0 + lane];
  }
  __syncthreads();
  unsigned* wb = wsu + (size_t)b * N_ * N_;
#pragma unroll
  for (int r = w; r < 64; r += 4) {
    wb[(size_t)(i0 + r) * N_ + j0 + lane] =
        (unsigned)(ta[r][lane] << 7) | ((unsigned)tb[lane][r] << 23);
  }
}

// ---------- kernel B: T = M' x h^T via MFMA (f32 in, f16 out), slot0 zeroing ----------
__global__ __launch_bounds__(256) void build_T_mfma(
    const float* __restrict__ h,      // [B][N][64] f32
    const float* __restrict__ Min,    // [8][64][64] f32
    const float* __restrict__ Mout,   // [8][64][64] f32
    unsigned short* __restrict__ Tin) {  // Tout = Tin + TOUT_OFF
  const int blk = blockIdx.x;               // 2048
  const int b   = (blk & 7) + 8 * ((blk >> 3) & 1);
  const int u   = blk >> 4;                 // 0..127
  const int kdt = u >> 3;                   // 0..15 : kd-tile of 64
  const int jt4 = u & 7;                    // 0..7
  const int w = threadIdx.x >> 6, l = threadIdx.x & 63;
  const int j0  = (jt4 * 4 + w) * 16;
  const int kd0 = kdt * 64;
  const int r16 = l & 15, grp = l >> 4;

  // B-operand: h row (j = j0 + r16), e-halves at grp*8 and grp*8+32
  const float* hrp = h + ((size_t)(b * N_ + j0 + r16)) * 64 + grp * 8;
  bf8_t hfr[2];
  hfr[0] = pack_bf8(hrp);
  hfr[1] = pack_bf8(hrp + 32);

  // A-operand: M rows (kd_local = (kd0&511) + fc*16 + r16), dir by kd0
  const float* Mbase = (kd0 >= 512) ? Mout : Min;
  const float* mrp = Mbase + (size_t)((kd0 & 511) + r16) * 64 + grp * 8;

  f4_t acc[4];
#pragma unroll
  for (int fc = 0; fc < 4; ++fc) acc[fc] = (f4_t)(0.f);
#pragma unroll
  for (int fc = 0; fc < 4; ++fc) {
    const bf8_t a0 = pack_bf8(mrp + (size_t)fc * 16 * 64);
    const bf8_t a1 = pack_bf8(mrp + (size_t)fc * 16 * 64 + 32);
    acc[fc] = __builtin_amdgcn_mfma_f32_16x16x32_bf16(a0, hfr[0], acc[fc], 0, 0, 0);
    acc[fc] = __builtin_amdgcn_mfma_f32_16x16x32_bf16(a1, hfr[1], acc[fc], 0, 0, 0);
  }

  unsigned short* Tb = Tin + ((kd0 >= 512) ? TOUT_OFF : 0) + (size_t)b * N_ * 576;
  const int kdl = kd0 & 511;
  const int j = j0 + r16;
  unsigned short* trow = Tb + (size_t)j * 576 + 64 + kdl + grp * 4;
#pragma unroll
  for (int fc = 0; fc < 4; ++fc) {
    const __half2 lo = __floats2half2_rn(acc[fc][0], acc[fc][1]);
    const __half2 hi = __floats2half2_rn(acc[fc][2], acc[fc][3]);
    uint2 pk;
    pk.x = *(const unsigned*)&lo;
    pk.y = *(const unsigned*)&hi;
    *(uint2*)(trow + fc * 16) = pk;
  }

  if (kdt == 0) {  // zero slot k=0 (128B per row per dir); covers every j once
    unsigned short* s0 = Tin + (size_t)b * N_ * 576 + (size_t)j * 576 + grp * 16;
    const int4 z = make_int4(0, 0, 0, 0);
    *(int4*)(s0)                 = z;
    *(int4*)(s0 + 8)             = z;
    *(int4*)(s0 + TOUT_OFF)      = z;
    *(int4*)(s0 + TOUT_OFF + 8)  = z;
  }
}

// ---------- kernel C: gather, 8 rows/block, wave-level j-split, LDS combine ----------
__global__ __launch_bounds__(512, 8) void gather_msg(
    const unsigned* __restrict__ wsu,
    const unsigned short* __restrict__ Tin,   // Tout contiguous after Tin
    const float* __restrict__ bias,
    float* __restrict__ out) {
  __shared__ unsigned ed[8 * 512];     // 16 KB edge words (reused as partial buf)
  const int blk = blockIdx.x;          // 1024
  const int b  = (blk & 7) + 8 * ((blk >> 3) & 1);
  const int rb = blk >> 4;             // 0..63 : row-block of 8
  const int tid = threadIdx.x;
  const int w = tid >> 6, lane = tid & 63;
  const int wq = w & 3, jh = w >> 2;   // j-half per wave group
  const int half = lane >> 5, lane5 = lane & 31;
  const int dir = lane5 >> 4;          // 0 = in, 1 = out
  const int dl  = lane5 & 15;          // d-quad (4 d's per lane)
  const int row_l = wq * 2 + half;     // 0..7

  {  // stage 8 rows x 512 edge words = 16 KB, contiguous
    const int4* src = (const int4*)(wsu + ((size_t)(b * N_ + rb * 8)) * N_);
    int4* dst = (int4*)ed;
    dst[tid]       = src[tid];
    dst[tid + 512] = src[tid + 512];
  }
  __syncthreads();

  const unsigned* edrow = ed + row_l * 512 + jh * 256;
  const unsigned shr_ = (unsigned)dir * 16u;
  const char* base = (const char*)Tin + (size_t)b * N_ * TROWB;
  unsigned vb = (unsigned)jh * 256u * (unsigned)TROWB +
                (unsigned)dir * (unsigned)T_BYTES + (unsigned)dl * 8u;

  float fa0 = 0.f, fa1 = 0.f, fa2 = 0.f, fa3 = 0.f;
  for (int jw = 0; jw < 4; ++jw) {           // 4 windows x 64 j
    __half2 a0 = __floats2half2_rn(0.f, 0.f);
    __half2 a1 = __floats2half2_rn(0.f, 0.f);
#pragma unroll
    for (int j4 = 0; j4 < 16; ++j4) {
      const uint4 ew = *(const uint4*)(edrow + jw * 64 + j4 * 4);
#pragma unroll
      for (int t = 0; t < 4; ++t) {
        const unsigned wvv = (t == 0) ? ew.x : (t == 1) ? ew.y : (t == 2) ? ew.z : ew.w;
        const unsigned off = (wvv >> shr_) & 0xFFFFu;
        const uint2 u = *(const uint2*)(base + (vb + off));
        a0 = __hadd2(a0, *(const __half2*)&u.x);
        a1 = __hadd2(a1, *(const __half2*)&u.y);
        vb += TROWB;
      }
    }
    const float2 f0 = __half22float2(a0);
    const float2 f1 = __half22float2(a1);
    fa0 += f0.x; fa1 += f0.y; fa2 += f1.x; fa3 += f1.y;
  }

  __syncthreads();                       // done with ed; reuse as partial buffer
  float4* pbuf = (float4*)ed;            // 256 float4 = 4 KB
  if (jh == 1) pbuf[wq * 64 + lane] = make_float4(fa0, fa1, fa2, fa3);
  __syncthreads();
  if (jh == 0) {
    const float4 p = pbuf[wq * 64 + lane];
    const int row = rb * 8 + row_l;
    const int d0 = dl * 4;
    float4 r;
    r.x = fa0 + p.x + bias[dir * 64 + d0];
    r.y = fa1 + p.y + bias[dir * 64 + d0 + 1];
    r.z = fa2 + p.z + bias[dir * 64 + d0 + 2];
    r.w = fa3 + p.w + bias[dir * 64 + d0 + 3];
    *(float4*)(out + ((size_t)b * N_ + row) * (2 * D_) + dir * 64 + d0) = r;
  }
}

// ---------- fallback (branch-tree kernel) if ws is too small ----------
#define ACCUM(kv, bucket) switch (kv) { \
    case 1: (bucket)[0] += v_; break; case 2: (bucket)[1] += v_; break; \
    case 3: (bucket)[2] += v_; break; case 4: (bucket)[3] += v_; break; \
    case 5: (bucket)[4] += v_; break; case 6: (bucket)[5] += v_; break; \
    case 7: (bucket)[6] += v_; break; case 8: (bucket)[7] += v_; break; \
    default: break; }

__global__ __launch_bounds__(64) void ggnn_fallback(
    const float* __restrict__ h, const int* __restrict__ adj,
    const float* __restrict__ Min, const float* __restrict__ Mout,
    const float* __restrict__ bias, float* __restrict__ out) {
  const int blk = blockIdx.x;
  const int b  = blk / (N_ / 2);
  const int i0 = (blk % (N_ / 2)) * 2;
  const int d  = threadIdx.x;
  float s_in[2][K_], s_out[2][K_];
#pragma unroll
  for (int r = 0; r < 2; ++r)
#pragma unroll
    for (int k = 0; k < K_; ++k) { s_in[r][k] = 0.f; s_out[r][k] = 0.f; }
  const int* rowp0 = adj + (b * N_ + i0) * N_;
  const int* rowp1 = rowp0 + N_;
  const int* colp  = adj + b * N_ * N_ + i0;
  const float* hb  = h + b * N_ * D_ + d;
  for (int j0 = 0; j0 < N_; j0 += 8) {
    float hv[8]; int kr0[8], kr1[8], kc0[8], kc1[8];
#pragma unroll
    for (int m = 0; m < 8; ++m) {
      hv[m] = hb[(j0 + m) * D_];
      kr0[m] = rowp0[j0 + m]; kr1[m] = rowp1[j0 + m];
      kc0[m] = colp[(j0 + m) * N_]; kc1[m] = colp[(j0 + m) * N_ + 1];
    }
#pragma unroll
    for (int m = 0; m < 8; ++m) {
      const float v_ = hv[m];
      ACCUM(kr0[m], s_in[0]); ACCUM(kr1[m], s_in[1]);
      ACCUM(kc0[m], s_out[0]); ACCUM(kc1[m], s_out[1]);
    }
  }
  __shared__ float S[2][2][K_][D_];
#pragma unroll
  for (int r = 0; r < 2; ++r)
#pragma unroll
    for (int k = 0; k < K_; ++k) { S[r][0][k][d] = s_in[r][k]; S[r][1][k][d] = s_out[r][k]; }
  __syncthreads();
  float acc_in[2], acc_out[2];
#pragma unroll
  for (int r = 0; r < 2; ++r) { acc_in[r] = bias[d]; acc_out[r] = bias[D_ + d]; }
  for (int k = 0; k < K_; ++k) {
#pragma unroll
    for (int e0 = 0; e0 < D_; e0 += 4) {
      const float4 mi = *(const float4*)(Min  + (k * D_ + d) * D_ + e0);
      const float4 mo = *(const float4*)(Mout + (k * D_ + d) * D_ + e0);
#pragma unroll
      for (int r = 0; r < 2; ++r) {
        const float4 si = *(const float4*)(&S[r][0][k][e0]);
        const float4 so = *(const float4*)(&S[r][1][k][e0]);
        acc_in[r]  += mi.x * si.x + mi.y * si.y + mi.z * si.z + mi.w * si.w;
        acc_out[r] += mo.x * so.x + mo.y * so.y + mo.z * so.z + mo.w * so.w;
      }
    }
  }
#pragma unroll
  for (int r = 0; r < 2; ++r) {
    out[(b * N_ + i0 + r) * (2 * D_) + d]      = acc_in[r];
    out[(b * N_ + i0 + r) * (2 * D_) + D_ + d] = acc_out[r];
  }
}

extern "C" void kernel_launch(void* const* d_in, const int* in_sizes, int n_in,
                              void* d_out, int out_size, void* d_ws, size_t ws_size,
                              hipStream_t stream) {
  const float* h    = (const float*)d_in[0];
  const int*   adj  = (const int*)d_in[1];
  const float* Min  = (const float*)d_in[3];
  const float* Mout = (const float*)d_in[4];
  const float* bias = (const float*)d_in[5];
  float* out = (float*)d_out;

  if (ws_size < WSU_BYTES + 2 * T_BYTES) {
    hipLaunchKernelGGL(ggnn_fallback, dim3(B_ * N_ / 2), dim3(64), 0, stream,
                       h, adj, Min, Mout, bias, out);
    return;
  }
  unsigned*       wsu = (unsigned*)d_ws;
  unsigned short* Tin = (unsigned short*)((char*)d_ws + WSU_BYTES);

  hipLaunchKernelGGL(prep_adj,     dim3(1024), dim3(256), 0, stream, adj, wsu);
  hipLaunchKernelGGL(build_T_mfma, dim3(2048), dim3(256), 0, stream, h, Min, Mout, Tin);
  hipLaunchKernelGGL(gather_msg,   dim3(1024), dim3(512), 0, stream, wsu, Tin, bias, out);
}

// Round 9
// 166.720 us; speedup vs baseline: 1.0313x; 1.0313x over previous
//
#include <hip/hip_runtime.h>
#include <hip/hip_fp16.h>

#define B_ 16
#define N_ 512
#define D_ 64
#define K_ 8

// ---------------- ws layout ----------------
// Tin : [B][N][9][64] f16    9,437,184 B
// Tout: [B][N][9][64] f16    (contiguous after Tin)
#define T_BYTES   ((size_t)B_ * N_ * (K_ + 1) * D_ * 2)
#define TROWB 1152              // (K+1)*D*2 bytes per j row
#define TOUT_OFF (T_BYTES / 2)  // Tout offset in ushorts

typedef __attribute__((ext_vector_type(8))) short bf8_t;   // 8 bf16
typedef __attribute__((ext_vector_type(4))) float f4_t;    // 4 f32 acc

__device__ __forceinline__ unsigned short f2bf(float x) {  // RNE f32->bf16
  union { float f; unsigned u; } c; c.f = x;
  unsigned r = c.u + 0x7FFFu + ((c.u >> 16) & 1u);
  return (unsigned short)(r >> 16);
}

__device__ __forceinline__ bf8_t pack_bf8(const float* p) {  // 8 f32 -> 8 bf16
  const float4 a = *(const float4*)p;
  const float4 b = *(const float4*)(p + 4);
  union { unsigned u[4]; bf8_t v; } r;
  r.u[0] = (unsigned)f2bf(a.x) | ((unsigned)f2bf(a.y) << 16);
  r.u[1] = (unsigned)f2bf(a.z) | ((unsigned)f2bf(a.w) << 16);
  r.u[2] = (unsigned)f2bf(b.x) | ((unsigned)f2bf(b.y) << 16);
  r.u[3] = (unsigned)f2bf(b.z) | ((unsigned)f2bf(b.w) << 16);
  return r.v;
}

// ---------- kernel B: T = M' x h^T via MFMA (f32 in, f16 out), slot0 zeroing ----------
__global__ __launch_bounds__(256) void build_T_mfma(
    const float* __restrict__ h,      // [B][N][64] f32
    const float* __restrict__ Min,    // [8][64][64] f32
    const float* __restrict__ Mout,   // [8][64][64] f32
    unsigned short* __restrict__ Tin) {  // Tout = Tin + TOUT_OFF
  const int blk = blockIdx.x;               // 2048
  const int b   = (blk & 7) + 8 * ((blk >> 3) & 1);
  const int u   = blk >> 4;                 // 0..127
  const int kdt = u >> 3;                   // 0..15 : kd-tile of 64
  const int jt4 = u & 7;                    // 0..7
  const int w = threadIdx.x >> 6, l = threadIdx.x & 63;
  const int j0  = (jt4 * 4 + w) * 16;
  const int kd0 = kdt * 64;
  const int r16 = l & 15, grp = l >> 4;

  const float* hrp = h + ((size_t)(b * N_ + j0 + r16)) * 64 + grp * 8;
  bf8_t hfr[2];
  hfr[0] = pack_bf8(hrp);
  hfr[1] = pack_bf8(hrp + 32);

  const float* Mbase = (kd0 >= 512) ? Mout : Min;
  const float* mrp = Mbase + (size_t)((kd0 & 511) + r16) * 64 + grp * 8;

  f4_t acc[4];
#pragma unroll
  for (int fc = 0; fc < 4; ++fc) acc[fc] = (f4_t)(0.f);
#pragma unroll
  for (int fc = 0; fc < 4; ++fc) {
    const bf8_t a0 = pack_bf8(mrp + (size_t)fc * 16 * 64);
    const bf8_t a1 = pack_bf8(mrp + (size_t)fc * 16 * 64 + 32);
    acc[fc] = __builtin_amdgcn_mfma_f32_16x16x32_bf16(a0, hfr[0], acc[fc], 0, 0, 0);
    acc[fc] = __builtin_amdgcn_mfma_f32_16x16x32_bf16(a1, hfr[1], acc[fc], 0, 0, 0);
  }

  unsigned short* Tb = Tin + ((kd0 >= 512) ? TOUT_OFF : 0) + (size_t)b * N_ * 576;
  const int kdl = kd0 & 511;
  const int j = j0 + r16;
  unsigned short* trow = Tb + (size_t)j * 576 + 64 + kdl + grp * 4;
#pragma unroll
  for (int fc = 0; fc < 4; ++fc) {
    const __half2 lo = __floats2half2_rn(acc[fc][0], acc[fc][1]);
    const __half2 hi = __floats2half2_rn(acc[fc][2], acc[fc][3]);
    uint2 pk;
    pk.x = *(const unsigned*)&lo;
    pk.y = *(const unsigned*)&hi;
    *(uint2*)(trow + fc * 16) = pk;
  }

  if (kdt == 0) {  // zero slot k=0 (128B per row per dir); covers every j once
    unsigned short* s0 = Tin + (size_t)b * N_ * 576 + (size_t)j * 576 + grp * 16;
    const int4 z = make_int4(0, 0, 0, 0);
    *(int4*)(s0)                 = z;
    *(int4*)(s0 + 8)             = z;
    *(int4*)(s0 + TOUT_OFF)      = z;
    *(int4*)(s0 + TOUT_OFF + 8)  = z;
  }
}

// ---------- kernel C: fused gather, 16 rows/block, in-kernel adj transpose ----------
// Lane layout: 8 waves x (2 rows x 2 dirs x 16 d-quads) = 16 rows, full j sweep.
// Edge windows (64 j) double-buffered in LDS; kout tile transposed on LDS write.
__global__ __launch_bounds__(512, 4) void gather_fused(
    const int* __restrict__ adj,              // [B][N][N] int 0..8
    const unsigned short* __restrict__ Tin,   // Tout contiguous after Tin
    const float* __restrict__ bias,
    float* __restrict__ out) {
  __shared__ int ed [2][16][72];   // kin  rows  [row][j]   (stride 72: aligned+bank-spread)
  __shared__ int edT[2][16][72];   // kout rows  [row][j]   (transposed at write)
  const int blk = blockIdx.x;      // 512
  const int b  = (blk & 7) + 8 * ((blk >> 3) & 1);
  const int rb = blk >> 4;         // 0..31 : row-block of 16
  const int i0 = rb * 16;
  const int tid = threadIdx.x;
  const int w = tid >> 6, lane = tid & 63;
  const int half = lane >> 5, lane5 = lane & 31;
  const int dir = lane5 >> 4;      // 0 = in, 1 = out
  const int dl  = lane5 & 15;      // d-quad (4 d's per lane)
  const int row_l = w * 2 + half;  // 0..15

  const int* adjb = adj + (size_t)b * N_ * N_;

  // stager roles: threads 0-255 load kin (row-major), 256-511 load kout col-tile
  const bool s_kin = (tid < 256);
  const int sr  = tid >> 4, sc4 = (tid & 15) * 4;       // kin: row sr, j-offset sc4
  const int t2  = tid & 255;
  const int sjr = t2 >> 2, sc = (t2 & 3) * 4;           // kout: j-row sjr, i-offset sc

  // prologue: stage window 0
  if (s_kin) {
    const int4 v = *(const int4*)(adjb + (size_t)(i0 + sr) * N_ + sc4);
    *(int4*)&ed[0][sr][sc4] = v;
  } else {
    const int4 v = *(const int4*)(adjb + (size_t)sjr * N_ + i0 + sc);
    edT[0][sc][sjr] = v.x; edT[0][sc + 1][sjr] = v.y;
    edT[0][sc + 2][sjr] = v.z; edT[0][sc + 3][sjr] = v.w;
  }
  __syncthreads();

  const char* tbase = (const char*)Tin + (size_t)b * N_ * TROWB;
  unsigned vb = (unsigned)dir * (unsigned)T_BYTES + (unsigned)dl * 8u;
  float fa0 = 0.f, fa1 = 0.f, fa2 = 0.f, fa3 = 0.f;
  int buf = 0;

  for (int win = 0; win < 8; ++win) {
    if (win < 7) {  // prefetch next window into buf^1
      const int j0n = (win + 1) * 64;
      if (s_kin) {
        const int4 v = *(const int4*)(adjb + (size_t)(i0 + sr) * N_ + j0n + sc4);
        *(int4*)&ed[buf ^ 1][sr][sc4] = v;
      } else {
        const int4 v = *(const int4*)(adjb + (size_t)(j0n + sjr) * N_ + i0 + sc);
        edT[buf ^ 1][sc][sjr] = v.x; edT[buf ^ 1][sc + 1][sjr] = v.y;
        edT[buf ^ 1][sc + 2][sjr] = v.z; edT[buf ^ 1][sc + 3][sjr] = v.w;
      }
    }

    const int* krow = dir ? &edT[buf][row_l][0] : &ed[buf][row_l][0];
    __half2 a0 = __floats2half2_rn(0.f, 0.f);
    __half2 a1 = __floats2half2_rn(0.f, 0.f);
#pragma unroll
    for (int j4 = 0; j4 < 16; ++j4) {
      const int4 kv4 = *(const int4*)&krow[j4 * 4];   // broadcast ds_read_b128
#pragma unroll
      for (int t = 0; t < 4; ++t) {
        const unsigned kv = (unsigned)((t == 0) ? kv4.x : (t == 1) ? kv4.y
                                      : (t == 2) ? kv4.z : kv4.w);
        const uint2 u = *(const uint2*)(tbase + (vb + (kv << 7)));
        a0 = __hadd2(a0, *(const __half2*)&u.x);
        a1 = __hadd2(a1, *(const __half2*)&u.y);
        vb += TROWB;
      }
    }
    const float2 f0 = __half22float2(a0);
    const float2 f1 = __half22float2(a1);
    fa0 += f0.x; fa1 += f0.y; fa2 += f1.x; fa3 += f1.y;

    __syncthreads();   // next window's staging (buf^1) complete; safe to swap
    buf ^= 1;
  }

  const int row = i0 + row_l;
  const int d0 = dl * 4;
  float4 r;
  r.x = fa0 + bias[dir * 64 + d0];
  r.y = fa1 + bias[dir * 64 + d0 + 1];
  r.z = fa2 + bias[dir * 64 + d0 + 2];
  r.w = fa3 + bias[dir * 64 + d0 + 3];
  *(float4*)(out + ((size_t)b * N_ + row) * (2 * D_) + dir * 64 + d0) = r;
}

// ---------- fallback (branch-tree kernel) if ws is too small ----------
#define ACCUM(kv, bucket) switch (kv) { \
    case 1: (bucket)[0] += v_; break; case 2: (bucket)[1] += v_; break; \
    case 3: (bucket)[2] += v_; break; case 4: (bucket)[3] += v_; break; \
    case 5: (bucket)[4] += v_; break; case 6: (bucket)[5] += v_; break; \
    case 7: (bucket)[6] += v_; break; case 8: (bucket)[7] += v_; break; \
    default: break; }

__global__ __launch_bounds__(64) void ggnn_fallback(
    const float* __restrict__ h, const int* __restrict__ adj,
    const float* __restrict__ Min, const float* __restrict__ Mout,
    const float* __restrict__ bias, float* __restrict__ out) {
  const int blk = blockIdx.x;
  const int b  = blk / (N_ / 2);
  const int i0 = (blk % (N_ / 2)) * 2;
  const int d  = threadIdx.x;
  float s_in[2][K_], s_out[2][K_];
#pragma unroll
  for (int r = 0; r < 2; ++r)
#pragma unroll
    for (int k = 0; k < K_; ++k) { s_in[r][k] = 0.f; s_out[r][k] = 0.f; }
  const int* rowp0 = adj + (b * N_ + i0) * N_;
  const int* rowp1 = rowp0 + N_;
  const int* colp  = adj + b * N_ * N_ + i0;
  const float* hb  = h + b * N_ * D_ + d;
  for (int j0 = 0; j0 < N_; j0 += 8) {
    float hv[8]; int kr0[8], kr1[8], kc0[8], kc1[8];
#pragma unroll
    for (int m = 0; m < 8; ++m) {
      hv[m] = hb[(j0 + m) * D_];
      kr0[m] = rowp0[j0 + m]; kr1[m] = rowp1[j0 + m];
      kc0[m] = colp[(j0 + m) * N_]; kc1[m] = colp[(j0 + m) * N_ + 1];
    }
#pragma unroll
    for (int m = 0; m < 8; ++m) {
      const float v_ = hv[m];
      ACCUM(kr0[m], s_in[0]); ACCUM(kr1[m], s_in[1]);
      ACCUM(kc0[m], s_out[0]); ACCUM(kc1[m], s_out[1]);
    }
  }
  __shared__ float S[2][2][K_][D_];
#pragma unroll
  for (int r = 0; r < 2; ++r)
#pragma unroll
    for (int k = 0; k < K_; ++k) { S[r][0][k][d] = s_in[r][k]; S[r][1][k][d] = s_out[r][k]; }
  __syncthreads();
  float acc_in[2], acc_out[2];
#pragma unroll
  for (int r = 0; r < 2; ++r) { acc_in[r] = bias[d]; acc_out[r] = bias[D_ + d]; }
  for (int k = 0; k < K_; ++k) {
#pragma unroll
    for (int e0 = 0; e0 < D_; e0 += 4) {
      const float4 mi = *(const float4*)(Min  + (k * D_ + d) * D_ + e0);
      const float4 mo = *(const float4*)(Mout + (k * D_ + d) * D_ + e0);
#pragma unroll
      for (int r = 0; r < 2; ++r) {
        const float4 si = *(const float4*)(&S[r][0][k][e0]);
        const float4 so = *(const float4*)(&S[r][1][k][e0]);
        acc_in[r]  += mi.x * si.x + mi.y * si.y + mi.z * si.z + mi.w * si.w;
        acc_out[r] += mo.x * so.x + mo.y * so.y + mo.z * so.z + mo.w * so.w;
      }
    }
  }
#pragma unroll
  for (int r = 0; r < 2; ++r) {
    out[(b * N_ + i0 + r) * (2 * D_) + d]      = acc_in[r];
    out[(b * N_ + i0 + r) * (2 * D_) + D_ + d] = acc_out[r];
  }
}

extern "C" void kernel_launch(void* const* d_in, const int* in_sizes, int n_in,
                              void* d_out, int out_size, void* d_ws, size_t ws_size,
                              hipStream_t stream) {
  const float* h    = (const float*)d_in[0];
  const int*   adj  = (const int*)d_in[1];
  const float* Min  = (const float*)d_in[3];
  const float* Mout = (const float*)d_in[4];
  const float* bias = (const float*)d_in[5];
  float* out = (float*)d_out;

  if (ws_size < 2 * T_BYTES) {
    hipLaunchKernelGGL(ggnn_fallback, dim3(B_ * N_ / 2), dim3(64), 0, stream,
                       h, adj, Min, Mout, bias, out);
    return;
  }
  unsigned short* Tin = (unsigned short*)d_ws;

  hipLaunchKernelGGL(build_T_mfma, dim3(2048), dim3(256), 0, stream, h, Min, Mout, Tin);
  hipLaunchKernelGGL(gather_fused, dim3(512),  dim3(512), 0, stream, adj, Tin, bias, out);
}